// Round 1
// baseline (281.317 us; speedup 1.0000x reference)
//
#include <hip/hip_runtime.h>

#define TILE 32
#define GS_DIM 34        // TILE+2 (blur halo)
#define GS_STRIDE 35
#define PR_DIM 36        // TILE+4 (conv halo on top of blur halo)
#define PR_STRIDE 37
#define HW 256
#define OW 254           // H-2
#define NOUT (256.0f * 254.0f * 254.0f)

__global__ __launch_bounds__(256) void pde_loss_main(
    const float* __restrict__ pred,
    const float* __restrict__ rhs,
    const float* __restrict__ Lk,
    const float* __restrict__ Dk,
    const float* __restrict__ RR,
    const float* __restrict__ ZZ,
    float* __restrict__ partial)
{
    __shared__ float sPred[PR_DIM * PR_STRIDE];
    __shared__ float sGS[GS_DIM * GS_STRIDE];
    __shared__ float sK[19];   // [0..8]=L, [9..17]=D, [18]=scale

    const int b  = blockIdx.z;
    const int i0 = blockIdx.y * TILE;
    const int j0 = blockIdx.x * TILE;
    const int tid = threadIdx.x;

    const float* predb = pred + (size_t)b * (HW * HW);
    const float* RRb   = RR   + (size_t)b * (HW * HW);
    const float* ZZb   = ZZ   + (size_t)b * (HW * HW);

    if (tid < 9) {
        sK[tid] = Lk[b * 9 + tid];
    } else if (tid < 18) {
        sK[tid] = Dk[b * 9 + (tid - 9)];
    } else if (tid == 18) {
        float hr = RRb[1 * HW + 2] - RRb[1 * HW + 1];
        float hz = ZZb[2 * HW + 1] - ZZb[1 * HW + 1];
        float hr2 = hr * hr, hz2 = hz * hz;
        sK[18] = (-2.0f * (hr2 + hz2)) / (hr2 * hz2);
    }

    // Stage pred tile (rows i0-1 .. i0+34, cols j0-1 .. j0+34), clamped.
    // Clamped cells are never consumed by an in-range GS point.
    for (int idx = tid; idx < PR_DIM * PR_DIM; idx += 256) {
        int r = idx / PR_DIM, c = idx - r * PR_DIM;
        int gr = i0 - 1 + r; gr = max(0, min(HW - 1, gr));
        int gc = j0 - 1 + c; gc = max(0, min(HW - 1, gc));
        sPred[r * PR_STRIDE + c] = predb[gr * HW + gc];
    }
    __syncthreads();

    const float scale = sK[18];

    // GS_ope on the 34x34 halo tile; zero outside [0,254)^2 (SAME zero-pad).
    for (int idx = tid; idx < GS_DIM * GS_DIM; idx += 256) {
        int gy = idx / GS_DIM, gx = idx - gy * GS_DIM;
        int y = i0 - 1 + gy, x = j0 - 1 + gx;
        float g = 0.0f;
        if (y >= 0 && y < OW && x >= 0 && x < OW) {
            const float* p = &sPred[gy * PR_STRIDE + gx];
            float sL = 0.0f, sD = 0.0f;
            #pragma unroll
            for (int ky = 0; ky < 3; ky++) {
                #pragma unroll
                for (int kx = 0; kx < 3; kx++) {
                    float v = p[ky * PR_STRIDE + kx];
                    sL += v * sK[ky * 3 + kx];
                    sD += v * sK[9 + ky * 3 + kx];
                }
            }
            float rr = RRb[(y + 1) * HW + (x + 1)];
            // GS = Lpsi - (-convD/RR) = Lpsi + convD/RR, then * scale
            g = scale * (sL + sD / rr);
        }
        sGS[gy * GS_STRIDE + gx] = g;
    }
    __syncthreads();

    // Blur (1,2,1;2,4,2;1,2,1)/16 + MSE accumulate, 4 outputs/thread.
    float acc = 0.0f;
    #pragma unroll
    for (int k = 0; k < 4; k++) {
        int o  = tid + k * 256;
        int oy = o >> 5, ox = o & 31;
        int i = i0 + oy, j = j0 + ox;
        if (i < OW && j < OW) {
            const float* gp = &sGS[oy * GS_STRIDE + ox];
            float F = (gp[0] + gp[2] + gp[2 * GS_STRIDE] + gp[2 * GS_STRIDE + 2])
                    + 2.0f * (gp[1] + gp[GS_STRIDE] + gp[GS_STRIDE + 2] + gp[2 * GS_STRIDE + 1])
                    + 4.0f * gp[GS_STRIDE + 1];
            F *= (1.0f / 16.0f);
            float d = F - rhs[(size_t)b * (OW * OW) + i * OW + j];
            acc += d * d;
        }
    }

    // wave (64) + block reduce
    #pragma unroll
    for (int off = 32; off > 0; off >>= 1)
        acc += __shfl_down(acc, off, 64);
    __shared__ float sw[4];
    int lane = tid & 63, w = tid >> 6;
    if (lane == 0) sw[w] = acc;
    __syncthreads();
    if (tid == 0) {
        partial[((size_t)blockIdx.z * gridDim.y + blockIdx.y) * gridDim.x + blockIdx.x]
            = sw[0] + sw[1] + sw[2] + sw[3];
    }
}

__global__ __launch_bounds__(256) void pde_loss_reduce(
    const float* __restrict__ partial, int n, float* __restrict__ out)
{
    float acc = 0.0f;
    for (int i = threadIdx.x; i < n; i += 256) acc += partial[i];
    #pragma unroll
    for (int off = 32; off > 0; off >>= 1)
        acc += __shfl_down(acc, off, 64);
    __shared__ float sw[4];
    if ((threadIdx.x & 63) == 0) sw[threadIdx.x >> 6] = acc;
    __syncthreads();
    if (threadIdx.x == 0)
        out[0] = (sw[0] + sw[1] + sw[2] + sw[3]) / NOUT;
}

extern "C" void kernel_launch(void* const* d_in, const int* in_sizes, int n_in,
                              void* d_out, int out_size, void* d_ws, size_t ws_size,
                              hipStream_t stream) {
    const float* pred = (const float*)d_in[0];
    const float* rhs  = (const float*)d_in[1];
    const float* Lk   = (const float*)d_in[2];
    const float* Dk   = (const float*)d_in[3];
    const float* RR   = (const float*)d_in[4];
    const float* ZZ   = (const float*)d_in[5];
    float* out = (float*)d_out;
    float* partial = (float*)d_ws;   // 8*8*256 = 16384 floats = 64 KiB

    dim3 grid(8, 8, 256);            // ceil(254/32)=8 tiles per dim, 256 batches
    pde_loss_main<<<grid, 256, 0, stream>>>(pred, rhs, Lk, Dk, RR, ZZ, partial);
    pde_loss_reduce<<<1, 256, 0, stream>>>(partial, 8 * 8 * 256, out);
}